// Round 16
// baseline (105.111 us; speedup 1.0000x reference)
//
#include <hip/hip_runtime.h>

// GCN scatter-add: out[v] = sum_{(u,v) in E} features[u]
// Pipeline (4 dispatches):
//   1. hist (489 blocks; also zeroes ticket)
//   2. scan_a (wave-per-bucket column prefix) + ticketed scan_b (bases)
//   3. [partition | convert] disjoint-role fused
//   4. quarter-bucket bf16 gather

#define N_NODES   100000
#define N_EDGES   1000000
#define D_FEAT    64
#define NPB       128                 // nodes per partition bucket
#define NPB_SHIFT 7
#define NB        782                 // ceil(100000/128)
#define EPB       2048                // edges per hist/partition block
#define CH        2048                // pairs chunk per gather iteration

typedef unsigned int uint;
typedef unsigned short ushort;

__device__ inline ushort f2bf(float f) {   // RNE f32 -> bf16
    uint u = __float_as_uint(f);
    uint lsb = (u >> 16) & 1u;
    u += 0x7fffu + lsb;
    return (ushort)(u >> 16);
}

// Bucket histogram: 489 blocks, one int4 per thread, LDS-aggregated,
// plain coalesced row store. Block 0 also re-zeroes the ticket.
__global__ __launch_bounds__(512) void hist_kernel(const int* __restrict__ dst,
                                                   int* __restrict__ cnt_table,
                                                   int* __restrict__ ticket, int n) {
    __shared__ int cnt[NB];
    int t = threadIdx.x;
    if (blockIdx.x == 0 && t == 0)
        __hip_atomic_store(ticket, 0, __ATOMIC_RELAXED, __HIP_MEMORY_SCOPE_AGENT);
    for (int i = t; i < NB; i += 512) cnt[i] = 0;
    __syncthreads();
    int idx = blockIdx.x * EPB + t * 4;
    if (idx < n) {   // n % 4 == 0 -> full int4 valid
        int4 d = *reinterpret_cast<const int4*>(dst + idx);
        atomicAdd(&cnt[d.x >> NPB_SHIFT], 1);
        atomicAdd(&cnt[d.y >> NPB_SHIFT], 1);
        atomicAdd(&cnt[d.z >> NPB_SHIFT], 1);
        atomicAdd(&cnt[d.w >> NPB_SHIFT], 1);
    }
    __syncthreads();
    for (int b = t; b < NB; b += 512) cnt_table[blockIdx.x * NB + b] = cnt[b];
}

// scan_a: one wave per bucket (16 waves/block, 49 blocks); shfl parallel
// prefix over the bucket's 489-row column IN-PLACE; bucket total -> btot.
// Last-finishing block (ticket) then scans btot -> bases (the old scan_b).
__global__ __launch_bounds__(1024) void scan_kernel(int* __restrict__ cnt_table,
                                                    int* __restrict__ btot,
                                                    int* __restrict__ bases,
                                                    int* __restrict__ ticket,
                                                    int n_edges, int pb_rows, int nblocks) {
    __shared__ int lds[1024];
    __shared__ int isLast;
    int t = threadIdx.x;
    int wave = t >> 6, lane = t & 63;
    int bucket = blockIdx.x * 16 + wave;

    if (bucket < NB) {
        int run = 0;
#pragma unroll
        for (int c = 0; c < 8; ++c) {          // 8*64 = 512 >= 489 rows
            int r = c * 64 + lane;
            int orig = (r < pb_rows) ? cnt_table[r * NB + bucket] : 0;
            int v = orig;
#pragma unroll
            for (int d = 1; d < 64; d <<= 1) {
                int u = __shfl_up(v, d);
                if (lane >= d) v += u;
            }
            if (r < pb_rows) cnt_table[r * NB + bucket] = v - orig + run;  // exclusive
            run += __shfl(v, 63);
        }
        if (lane == 0)
            __hip_atomic_store(&btot[bucket], run, __ATOMIC_RELAXED,
                               __HIP_MEMORY_SCOPE_AGENT);
    }

    __threadfence();
    __syncthreads();
    if (t == 0) isLast = (atomicAdd(ticket, 1) == nblocks - 1);
    __syncthreads();
    if (!isLast) return;

    // ---- scan_b body: exclusive scan of 782 bucket totals -> bases ----
    int v = (t < NB) ? __hip_atomic_load(&btot[t], __ATOMIC_RELAXED,
                                         __HIP_MEMORY_SCOPE_AGENT) : 0;
    lds[t] = v;
    __syncthreads();
    for (int off = 1; off < 1024; off <<= 1) {
        int u = (t >= off) ? lds[t - off] : 0;
        __syncthreads();
        lds[t] += u;
        __syncthreads();
    }
    if (t < NB) bases[t] = lds[t] - v;
    if (t == 0) bases[NB] = n_edges;
}

// Disjoint-role fused: blocks [0,pblocks) partition edges into pairs
// (LDS cursors seeded from bases + cnt_table prefix; one LDS atomic + one
// write per edge); blocks [pblocks,...) convert features to bf16.
__global__ __launch_bounds__(512) void part_conv_kernel(const int* __restrict__ src,
                                                        const int* __restrict__ dst,
                                                        const int* __restrict__ bases,
                                                        const int* __restrict__ cnt_table,
                                                        int* __restrict__ pairs,
                                                        const float* __restrict__ feat,
                                                        ushort* __restrict__ bfeat,
                                                        int n_edges, int n4, int pblocks) {
    __shared__ int cur[NB];
    int t = threadIdx.x;

    if ((int)blockIdx.x >= pblocks) {
        // ---- convert role ----
        int i = ((int)blockIdx.x - pblocks) * 512 + t;
        if (i < n4) {
            float4 v = ((const float4*)feat)[i];
            ushort4 o;
            o.x = f2bf(v.x); o.y = f2bf(v.y); o.z = f2bf(v.z); o.w = f2bf(v.w);
            ((ushort4*)bfeat)[i] = o;
        }
        return;
    }

    // ---- partition role ----
    for (int b = t; b < NB; b += 512)
        cur[b] = bases[b] + cnt_table[blockIdx.x * NB + b];
    __syncthreads();

    int idx = blockIdx.x * EPB + t * 4;
    if (idx < n_edges) {
        int4 s = *reinterpret_cast<const int4*>(src + idx);
        int4 d = *reinterpret_cast<const int4*>(dst + idx);
        int b, p;
        b = d.x >> NPB_SHIFT; p = atomicAdd(&cur[b], 1); pairs[p] = (s.x << NPB_SHIFT) | (d.x & (NPB - 1));
        b = d.y >> NPB_SHIFT; p = atomicAdd(&cur[b], 1); pairs[p] = (s.y << NPB_SHIFT) | (d.y & (NPB - 1));
        b = d.z >> NPB_SHIFT; p = atomicAdd(&cur[b], 1); pairs[p] = (s.z << NPB_SHIFT) | (d.z & (NPB - 1));
        b = d.w >> NPB_SHIFT; p = atomicAdd(&cur[b], 1); pairs[p] = (s.w << NPB_SHIFT) | (d.w & (NPB - 1));
    }
}

__device__ inline float4 bf4_to_f4(uint2 v) {
    float4 r;
    r.x = __uint_as_float(v.x << 16);
    r.y = __uint_as_float(v.x & 0xffff0000u);
    r.z = __uint_as_float(v.y << 16);
    r.w = __uint_as_float(v.y & 0xffff0000u);
    return r;
}

// Quarter-bucket gather over bf16 rows (unchanged).
__global__ __launch_bounds__(256) void gather16_kernel(const ushort* __restrict__ bfeat,
                                                       const int* __restrict__ bases,
                                                       const int* __restrict__ pairs,
                                                       float* __restrict__ out,
                                                       int n_nodes) {
    __shared__ int pbuf[CH];
    __shared__ int sorted[CH];
    __shared__ int deg[32];
    __shared__ int sc[32];
    __shared__ int start[33];
    __shared__ int cur[32];

    int bb = blockIdx.x >> 2;
    int q  = blockIdx.x & 3;
    int t = threadIdx.x;
    int grp = t >> 4;                // 16 groups of 16 lanes
    int l16 = t & 15;
    int lo = bases[bb], hi = bases[bb + 1];
    int node0 = bb * NPB + q * 32;

    bool first = true;
    for (int c = lo; c < hi || first; c += CH) {
        int n = hi - c;
        if (n > CH) n = CH;
        if (n < 0) n = 0;

        if (t < 32) deg[t] = 0;
        __syncthreads();
        for (int i = t; i < n; i += 256) {
            int p = pairs[c + i];
            pbuf[i] = p;
            int r = p & (NPB - 1);
            if ((r >> 5) == q) atomicAdd(&deg[r & 31], 1);
        }
        __syncthreads();
        if (t < 32) sc[t] = deg[t];
        __syncthreads();
        for (int off = 1; off < 32; off <<= 1) {
            int u = (t < 32 && t >= off) ? sc[t - off] : 0;
            __syncthreads();
            if (t < 32) sc[t] += u;
            __syncthreads();
        }
        if (t < 32) { start[t + 1] = sc[t]; cur[t] = sc[t] - deg[t]; }
        if (t == 0) start[0] = 0;
        __syncthreads();
        for (int i = t; i < n; i += 256) {
            int p = pbuf[i];
            int r = p & (NPB - 1);
            if ((r >> 5) == q) {
                int pos = atomicAdd(&cur[r & 31], 1);
                sorted[pos] = p >> NPB_SHIFT;
            }
        }
        __syncthreads();

        for (int r = grp; r < 32; r += 16) {
            int s0 = start[r], e0 = start[r + 1];
            float4 a0 = {0.f, 0.f, 0.f, 0.f}, a1 = a0, a2 = a0, a3 = a0;
            int i = s0;
            for (; i + 4 <= e0; i += 4) {
                int n0 = sorted[i], n1 = sorted[i + 1];
                int n2 = sorted[i + 2], n3 = sorted[i + 3];
                uint2 w0 = *reinterpret_cast<const uint2*>(bfeat + (size_t)n0 * D_FEAT + l16 * 4);
                uint2 w1 = *reinterpret_cast<const uint2*>(bfeat + (size_t)n1 * D_FEAT + l16 * 4);
                uint2 w2 = *reinterpret_cast<const uint2*>(bfeat + (size_t)n2 * D_FEAT + l16 * 4);
                uint2 w3 = *reinterpret_cast<const uint2*>(bfeat + (size_t)n3 * D_FEAT + l16 * 4);
                float4 v0 = bf4_to_f4(w0), v1 = bf4_to_f4(w1);
                float4 v2 = bf4_to_f4(w2), v3 = bf4_to_f4(w3);
                a0.x += v0.x; a0.y += v0.y; a0.z += v0.z; a0.w += v0.w;
                a1.x += v1.x; a1.y += v1.y; a1.z += v1.z; a1.w += v1.w;
                a2.x += v2.x; a2.y += v2.y; a2.z += v2.z; a2.w += v2.w;
                a3.x += v3.x; a3.y += v3.y; a3.z += v3.z; a3.w += v3.w;
            }
            for (; i < e0; ++i) {
                uint2 w = *reinterpret_cast<const uint2*>(bfeat + (size_t)sorted[i] * D_FEAT + l16 * 4);
                float4 v = bf4_to_f4(w);
                a0.x += v.x; a0.y += v.y; a0.z += v.z; a0.w += v.w;
            }
            float4 acc;
            acc.x = (a0.x + a1.x) + (a2.x + a3.x);
            acc.y = (a0.y + a1.y) + (a2.y + a3.y);
            acc.z = (a0.z + a1.z) + (a2.z + a3.z);
            acc.w = (a0.w + a1.w) + (a2.w + a3.w);

            int node = node0 + r;
            if (node < n_nodes) {
                float* o = out + (size_t)node * D_FEAT + l16 * 4;
                if (first) {
                    *reinterpret_cast<float4*>(o) = acc;
                } else {  // rare: bucket spans multiple chunks
                    atomicAdd(o + 0, acc.x); atomicAdd(o + 1, acc.y);
                    atomicAdd(o + 2, acc.z); atomicAdd(o + 3, acc.w);
                }
            }
        }
        first = false;
        __syncthreads();
    }
}

// fp32 fallback gather if ws can't fit the bf16 cache (same structure).
__global__ __launch_bounds__(256) void gather32_kernel(const float* __restrict__ feat,
                                                       const int* __restrict__ bases,
                                                       const int* __restrict__ pairs,
                                                       float* __restrict__ out,
                                                       int n_nodes) {
    __shared__ int pbuf[CH];
    __shared__ int sorted[CH];
    __shared__ int deg[32];
    __shared__ int sc[32];
    __shared__ int start[33];
    __shared__ int cur[32];

    int bb = blockIdx.x >> 2;
    int q  = blockIdx.x & 3;
    int t = threadIdx.x;
    int grp = t >> 4, l16 = t & 15;
    int lo = bases[bb], hi = bases[bb + 1];
    int node0 = bb * NPB + q * 32;

    bool first = true;
    for (int c = lo; c < hi || first; c += CH) {
        int n = hi - c;
        if (n > CH) n = CH;
        if (n < 0) n = 0;

        if (t < 32) deg[t] = 0;
        __syncthreads();
        for (int i = t; i < n; i += 256) {
            int p = pairs[c + i];
            pbuf[i] = p;
            int r = p & (NPB - 1);
            if ((r >> 5) == q) atomicAdd(&deg[r & 31], 1);
        }
        __syncthreads();
        if (t < 32) sc[t] = deg[t];
        __syncthreads();
        for (int off = 1; off < 32; off <<= 1) {
            int u = (t < 32 && t >= off) ? sc[t - off] : 0;
            __syncthreads();
            if (t < 32) sc[t] += u;
            __syncthreads();
        }
        if (t < 32) { start[t + 1] = sc[t]; cur[t] = sc[t] - deg[t]; }
        if (t == 0) start[0] = 0;
        __syncthreads();
        for (int i = t; i < n; i += 256) {
            int p = pbuf[i];
            int r = p & (NPB - 1);
            if ((r >> 5) == q) {
                int pos = atomicAdd(&cur[r & 31], 1);
                sorted[pos] = p >> NPB_SHIFT;
            }
        }
        __syncthreads();

        for (int r = grp; r < 32; r += 16) {
            int s0 = start[r], e0 = start[r + 1];
            float4 a0 = {0.f, 0.f, 0.f, 0.f};
            for (int i = s0; i < e0; ++i) {
                const float4 v = *reinterpret_cast<const float4*>(feat + (size_t)sorted[i] * D_FEAT + l16 * 4);
                a0.x += v.x; a0.y += v.y; a0.z += v.z; a0.w += v.w;
            }
            int node = node0 + r;
            if (node < n_nodes) {
                float* o = out + (size_t)node * D_FEAT + l16 * 4;
                if (first) *reinterpret_cast<float4*>(o) = a0;
                else {
                    atomicAdd(o + 0, a0.x); atomicAdd(o + 1, a0.y);
                    atomicAdd(o + 2, a0.z); atomicAdd(o + 3, a0.w);
                }
            }
        }
        first = false;
        __syncthreads();
    }
}

extern "C" void kernel_launch(void* const* d_in, const int* in_sizes, int n_in,
                              void* d_out, int out_size, void* d_ws, size_t ws_size,
                              hipStream_t stream) {
    const float* feat = (const float*)d_in[0];
    const int*   src  = (const int*)d_in[1];
    const int*   dst  = (const int*)d_in[2];
    float*       out  = (float*)d_out;

    const int n_edges = in_sizes[1];
    const int pblocks = (n_edges + EPB - 1) / EPB;  // 489
    const int n4 = N_NODES * D_FEAT / 4;            // 1.6M float4 groups
    const int cblocks = (n4 + 511) / 512;           // 3125
    const int sblocks = (NB + 15) / 16;             // 49

    // Workspace: cnt_table[pblocks*NB] | btot[NB] | bases[NB+1] | ticket | pairs[E] | bfeat
    int* cnt_table = (int*)d_ws;
    int* btot      = cnt_table + (size_t)pblocks * NB;
    int* bases     = btot + NB;
    int* ticket    = bases + NB + 1;
    int* pairs     = ticket + 1;
    size_t int_cnt = (size_t)pblocks * NB + NB + (NB + 1) + 1 + (size_t)n_edges;
    size_t bf_off  = (int_cnt * 4 + 7) & ~(size_t)7;  // 8B-aligned
    ushort* bfeat  = (ushort*)((char*)d_ws + bf_off);
    size_t need = bf_off + (size_t)N_NODES * D_FEAT * 2;

    hist_kernel<<<pblocks, 512, 0, stream>>>(dst, cnt_table, ticket, n_edges);
    scan_kernel<<<sblocks, 1024, 0, stream>>>(cnt_table, btot, bases, ticket,
                                              n_edges, pblocks, sblocks);
    if (ws_size >= need) {
        part_conv_kernel<<<pblocks + cblocks, 512, 0, stream>>>(src, dst, bases, cnt_table,
                                                                pairs, feat, bfeat,
                                                                n_edges, n4, pblocks);
        gather16_kernel<<<NB * 4, 256, 0, stream>>>(bfeat, bases, pairs, out, N_NODES);
    } else {
        part_conv_kernel<<<pblocks, 512, 0, stream>>>(src, dst, bases, cnt_table,
                                                      pairs, feat, nullptr,
                                                      n_edges, n4, pblocks);
        gather32_kernel<<<NB * 4, 256, 0, stream>>>(feat, bases, pairs, out, N_NODES);
    }
}

// Round 17
// 74.130 us; speedup vs baseline: 1.4179x; 1.4179x over previous
//
#include <hip/hip_runtime.h>

// GCN scatter-add: out[v] = sum_{(u,v) in E} features[u]
// Pipeline (5 dispatches, no device-scope fences):
//   1. hist (489 blocks)
//   2. scan_a (wave-per-bucket column prefix, in-place)
//   3. scan_b (bucket totals -> bases)
//   4. [partition | convert] disjoint-role fused
//   5. quarter-bucket bf16 gather

#define N_NODES   100000
#define N_EDGES   1000000
#define D_FEAT    64
#define NPB       128                 // nodes per partition bucket
#define NPB_SHIFT 7
#define NB        782                 // ceil(100000/128)
#define EPB       2048                // edges per hist/partition block
#define CH        2048                // pairs chunk per gather iteration

typedef unsigned int uint;
typedef unsigned short ushort;

__device__ inline ushort f2bf(float f) {   // RNE f32 -> bf16
    uint u = __float_as_uint(f);
    uint lsb = (u >> 16) & 1u;
    u += 0x7fffu + lsb;
    return (ushort)(u >> 16);
}

// Bucket histogram: 489 blocks, one int4 per thread, LDS-aggregated,
// plain coalesced row store to cnt_table.
__global__ __launch_bounds__(512) void hist_kernel(const int* __restrict__ dst,
                                                   int* __restrict__ cnt_table, int n) {
    __shared__ int cnt[NB];
    int t = threadIdx.x;
    for (int i = t; i < NB; i += 512) cnt[i] = 0;
    __syncthreads();
    int idx = blockIdx.x * EPB + t * 4;
    if (idx < n) {   // n % 4 == 0 -> full int4 valid
        int4 d = *reinterpret_cast<const int4*>(dst + idx);
        atomicAdd(&cnt[d.x >> NPB_SHIFT], 1);
        atomicAdd(&cnt[d.y >> NPB_SHIFT], 1);
        atomicAdd(&cnt[d.z >> NPB_SHIFT], 1);
        atomicAdd(&cnt[d.w >> NPB_SHIFT], 1);
    }
    __syncthreads();
    for (int b = t; b < NB; b += 512) cnt_table[blockIdx.x * NB + b] = cnt[b];
}

// scan_a: one wave per bucket; shfl parallel prefix over the bucket's
// 489-row column IN-PLACE; bucket total -> btot.  (98 blocks x 512 thr)
__global__ __launch_bounds__(512) void scan_a_kernel(int* __restrict__ cnt_table,
                                                     int* __restrict__ btot, int pb_rows) {
    int t = threadIdx.x;
    int bucket = blockIdx.x * 8 + (t >> 6);
    int lane = t & 63;
    if (bucket >= NB) return;
    int run = 0;
#pragma unroll
    for (int c = 0; c < 8; ++c) {          // 8*64 = 512 >= 489 rows
        int r = c * 64 + lane;
        int orig = (r < pb_rows) ? cnt_table[r * NB + bucket] : 0;
        int v = orig;
#pragma unroll
        for (int d = 1; d < 64; d <<= 1) {
            int u = __shfl_up(v, d);
            if (lane >= d) v += u;
        }
        if (r < pb_rows) cnt_table[r * NB + bucket] = v - orig + run;  // exclusive
        run += __shfl(v, 63);
    }
    if (lane == 0) btot[bucket] = run;
}

// scan_b: exclusive scan of 782 bucket totals -> bases.
__global__ __launch_bounds__(1024) void scan_b_kernel(const int* __restrict__ btot,
                                                      int* __restrict__ bases, int n_edges) {
    __shared__ int lds[1024];
    int t = threadIdx.x;
    int v = (t < NB) ? btot[t] : 0;
    lds[t] = v;
    __syncthreads();
    for (int off = 1; off < 1024; off <<= 1) {
        int u = (t >= off) ? lds[t - off] : 0;
        __syncthreads();
        lds[t] += u;
        __syncthreads();
    }
    if (t < NB) bases[t] = lds[t] - v;
    if (t == 0) bases[NB] = n_edges;
}

// Disjoint-role fused: blocks [0,pblocks) partition edges into pairs
// (LDS cursors seeded from bases + cnt_table prefix; one LDS atomic + one
// write per edge); blocks [pblocks,...) convert features to bf16.
__global__ __launch_bounds__(512) void part_conv_kernel(const int* __restrict__ src,
                                                        const int* __restrict__ dst,
                                                        const int* __restrict__ bases,
                                                        const int* __restrict__ cnt_table,
                                                        int* __restrict__ pairs,
                                                        const float* __restrict__ feat,
                                                        ushort* __restrict__ bfeat,
                                                        int n_edges, int n4, int pblocks) {
    __shared__ int cur[NB];
    int t = threadIdx.x;

    if ((int)blockIdx.x >= pblocks) {
        // ---- convert role ----
        int i = ((int)blockIdx.x - pblocks) * 512 + t;
        if (i < n4) {
            float4 v = ((const float4*)feat)[i];
            ushort4 o;
            o.x = f2bf(v.x); o.y = f2bf(v.y); o.z = f2bf(v.z); o.w = f2bf(v.w);
            ((ushort4*)bfeat)[i] = o;
        }
        return;
    }

    // ---- partition role ----
    for (int b = t; b < NB; b += 512)
        cur[b] = bases[b] + cnt_table[blockIdx.x * NB + b];
    __syncthreads();

    int idx = blockIdx.x * EPB + t * 4;
    if (idx < n_edges) {
        int4 s = *reinterpret_cast<const int4*>(src + idx);
        int4 d = *reinterpret_cast<const int4*>(dst + idx);
        int b, p;
        b = d.x >> NPB_SHIFT; p = atomicAdd(&cur[b], 1); pairs[p] = (s.x << NPB_SHIFT) | (d.x & (NPB - 1));
        b = d.y >> NPB_SHIFT; p = atomicAdd(&cur[b], 1); pairs[p] = (s.y << NPB_SHIFT) | (d.y & (NPB - 1));
        b = d.z >> NPB_SHIFT; p = atomicAdd(&cur[b], 1); pairs[p] = (s.z << NPB_SHIFT) | (d.z & (NPB - 1));
        b = d.w >> NPB_SHIFT; p = atomicAdd(&cur[b], 1); pairs[p] = (s.w << NPB_SHIFT) | (d.w & (NPB - 1));
    }
}

__device__ inline float4 bf4_to_f4(uint2 v) {
    float4 r;
    r.x = __uint_as_float(v.x << 16);
    r.y = __uint_as_float(v.x & 0xffff0000u);
    r.z = __uint_as_float(v.y << 16);
    r.w = __uint_as_float(v.y & 0xffff0000u);
    return r;
}

// Quarter-bucket gather over bf16 rows (unchanged).
__global__ __launch_bounds__(256) void gather16_kernel(const ushort* __restrict__ bfeat,
                                                       const int* __restrict__ bases,
                                                       const int* __restrict__ pairs,
                                                       float* __restrict__ out,
                                                       int n_nodes) {
    __shared__ int pbuf[CH];
    __shared__ int sorted[CH];
    __shared__ int deg[32];
    __shared__ int sc[32];
    __shared__ int start[33];
    __shared__ int cur[32];

    int bb = blockIdx.x >> 2;
    int q  = blockIdx.x & 3;
    int t = threadIdx.x;
    int grp = t >> 4;                // 16 groups of 16 lanes
    int l16 = t & 15;
    int lo = bases[bb], hi = bases[bb + 1];
    int node0 = bb * NPB + q * 32;

    bool first = true;
    for (int c = lo; c < hi || first; c += CH) {
        int n = hi - c;
        if (n > CH) n = CH;
        if (n < 0) n = 0;

        if (t < 32) deg[t] = 0;
        __syncthreads();
        for (int i = t; i < n; i += 256) {
            int p = pairs[c + i];
            pbuf[i] = p;
            int r = p & (NPB - 1);
            if ((r >> 5) == q) atomicAdd(&deg[r & 31], 1);
        }
        __syncthreads();
        if (t < 32) sc[t] = deg[t];
        __syncthreads();
        for (int off = 1; off < 32; off <<= 1) {
            int u = (t < 32 && t >= off) ? sc[t - off] : 0;
            __syncthreads();
            if (t < 32) sc[t] += u;
            __syncthreads();
        }
        if (t < 32) { start[t + 1] = sc[t]; cur[t] = sc[t] - deg[t]; }
        if (t == 0) start[0] = 0;
        __syncthreads();
        for (int i = t; i < n; i += 256) {
            int p = pbuf[i];
            int r = p & (NPB - 1);
            if ((r >> 5) == q) {
                int pos = atomicAdd(&cur[r & 31], 1);
                sorted[pos] = p >> NPB_SHIFT;
            }
        }
        __syncthreads();

        for (int r = grp; r < 32; r += 16) {
            int s0 = start[r], e0 = start[r + 1];
            float4 a0 = {0.f, 0.f, 0.f, 0.f}, a1 = a0, a2 = a0, a3 = a0;
            int i = s0;
            for (; i + 4 <= e0; i += 4) {
                int n0 = sorted[i], n1 = sorted[i + 1];
                int n2 = sorted[i + 2], n3 = sorted[i + 3];
                uint2 w0 = *reinterpret_cast<const uint2*>(bfeat + (size_t)n0 * D_FEAT + l16 * 4);
                uint2 w1 = *reinterpret_cast<const uint2*>(bfeat + (size_t)n1 * D_FEAT + l16 * 4);
                uint2 w2 = *reinterpret_cast<const uint2*>(bfeat + (size_t)n2 * D_FEAT + l16 * 4);
                uint2 w3 = *reinterpret_cast<const uint2*>(bfeat + (size_t)n3 * D_FEAT + l16 * 4);
                float4 v0 = bf4_to_f4(w0), v1 = bf4_to_f4(w1);
                float4 v2 = bf4_to_f4(w2), v3 = bf4_to_f4(w3);
                a0.x += v0.x; a0.y += v0.y; a0.z += v0.z; a0.w += v0.w;
                a1.x += v1.x; a1.y += v1.y; a1.z += v1.z; a1.w += v1.w;
                a2.x += v2.x; a2.y += v2.y; a2.z += v2.z; a2.w += v2.w;
                a3.x += v3.x; a3.y += v3.y; a3.z += v3.z; a3.w += v3.w;
            }
            for (; i < e0; ++i) {
                uint2 w = *reinterpret_cast<const uint2*>(bfeat + (size_t)sorted[i] * D_FEAT + l16 * 4);
                float4 v = bf4_to_f4(w);
                a0.x += v.x; a0.y += v.y; a0.z += v.z; a0.w += v.w;
            }
            float4 acc;
            acc.x = (a0.x + a1.x) + (a2.x + a3.x);
            acc.y = (a0.y + a1.y) + (a2.y + a3.y);
            acc.z = (a0.z + a1.z) + (a2.z + a3.z);
            acc.w = (a0.w + a1.w) + (a2.w + a3.w);

            int node = node0 + r;
            if (node < n_nodes) {
                float* o = out + (size_t)node * D_FEAT + l16 * 4;
                if (first) {
                    *reinterpret_cast<float4*>(o) = acc;
                } else {  // rare: bucket spans multiple chunks
                    atomicAdd(o + 0, acc.x); atomicAdd(o + 1, acc.y);
                    atomicAdd(o + 2, acc.z); atomicAdd(o + 3, acc.w);
                }
            }
        }
        first = false;
        __syncthreads();
    }
}

// fp32 fallback gather if ws can't fit the bf16 cache (same structure).
__global__ __launch_bounds__(256) void gather32_kernel(const float* __restrict__ feat,
                                                       const int* __restrict__ bases,
                                                       const int* __restrict__ pairs,
                                                       float* __restrict__ out,
                                                       int n_nodes) {
    __shared__ int pbuf[CH];
    __shared__ int sorted[CH];
    __shared__ int deg[32];
    __shared__ int sc[32];
    __shared__ int start[33];
    __shared__ int cur[32];

    int bb = blockIdx.x >> 2;
    int q  = blockIdx.x & 3;
    int t = threadIdx.x;
    int grp = t >> 4, l16 = t & 15;
    int lo = bases[bb], hi = bases[bb + 1];
    int node0 = bb * NPB + q * 32;

    bool first = true;
    for (int c = lo; c < hi || first; c += CH) {
        int n = hi - c;
        if (n > CH) n = CH;
        if (n < 0) n = 0;

        if (t < 32) deg[t] = 0;
        __syncthreads();
        for (int i = t; i < n; i += 256) {
            int p = pairs[c + i];
            pbuf[i] = p;
            int r = p & (NPB - 1);
            if ((r >> 5) == q) atomicAdd(&deg[r & 31], 1);
        }
        __syncthreads();
        if (t < 32) sc[t] = deg[t];
        __syncthreads();
        for (int off = 1; off < 32; off <<= 1) {
            int u = (t < 32 && t >= off) ? sc[t - off] : 0;
            __syncthreads();
            if (t < 32) sc[t] += u;
            __syncthreads();
        }
        if (t < 32) { start[t + 1] = sc[t]; cur[t] = sc[t] - deg[t]; }
        if (t == 0) start[0] = 0;
        __syncthreads();
        for (int i = t; i < n; i += 256) {
            int p = pbuf[i];
            int r = p & (NPB - 1);
            if ((r >> 5) == q) {
                int pos = atomicAdd(&cur[r & 31], 1);
                sorted[pos] = p >> NPB_SHIFT;
            }
        }
        __syncthreads();

        for (int r = grp; r < 32; r += 16) {
            int s0 = start[r], e0 = start[r + 1];
            float4 a0 = {0.f, 0.f, 0.f, 0.f};
            for (int i = s0; i < e0; ++i) {
                const float4 v = *reinterpret_cast<const float4*>(feat + (size_t)sorted[i] * D_FEAT + l16 * 4);
                a0.x += v.x; a0.y += v.y; a0.z += v.z; a0.w += v.w;
            }
            int node = node0 + r;
            if (node < n_nodes) {
                float* o = out + (size_t)node * D_FEAT + l16 * 4;
                if (first) *reinterpret_cast<float4*>(o) = a0;
                else {
                    atomicAdd(o + 0, a0.x); atomicAdd(o + 1, a0.y);
                    atomicAdd(o + 2, a0.z); atomicAdd(o + 3, a0.w);
                }
            }
        }
        first = false;
        __syncthreads();
    }
}

extern "C" void kernel_launch(void* const* d_in, const int* in_sizes, int n_in,
                              void* d_out, int out_size, void* d_ws, size_t ws_size,
                              hipStream_t stream) {
    const float* feat = (const float*)d_in[0];
    const int*   src  = (const int*)d_in[1];
    const int*   dst  = (const int*)d_in[2];
    float*       out  = (float*)d_out;

    const int n_edges = in_sizes[1];
    const int pblocks = (n_edges + EPB - 1) / EPB;  // 489
    const int n4 = N_NODES * D_FEAT / 4;            // 1.6M float4 groups
    const int cblocks = (n4 + 511) / 512;           // 3125
    const int sablocks = (NB + 7) / 8;              // 98

    // Workspace: cnt_table[pblocks*NB] | btot[NB] | bases[NB+1] | pairs[E] | bfeat
    int* cnt_table = (int*)d_ws;
    int* btot      = cnt_table + (size_t)pblocks * NB;
    int* bases     = btot + NB;
    int* pairs     = bases + NB + 1;
    size_t int_cnt = (size_t)pblocks * NB + NB + (NB + 1) + (size_t)n_edges;
    size_t bf_off  = (int_cnt * 4 + 7) & ~(size_t)7;  // 8B-aligned
    ushort* bfeat  = (ushort*)((char*)d_ws + bf_off);
    size_t need = bf_off + (size_t)N_NODES * D_FEAT * 2;

    hist_kernel<<<pblocks, 512, 0, stream>>>(dst, cnt_table, n_edges);
    scan_a_kernel<<<sablocks, 512, 0, stream>>>(cnt_table, btot, pblocks);
    scan_b_kernel<<<1, 1024, 0, stream>>>(btot, bases, n_edges);
    if (ws_size >= need) {
        part_conv_kernel<<<pblocks + cblocks, 512, 0, stream>>>(src, dst, bases, cnt_table,
                                                                pairs, feat, bfeat,
                                                                n_edges, n4, pblocks);
        gather16_kernel<<<NB * 4, 256, 0, stream>>>(bfeat, bases, pairs, out, N_NODES);
    } else {
        part_conv_kernel<<<pblocks, 512, 0, stream>>>(src, dst, bases, cnt_table,
                                                      pairs, feat, nullptr,
                                                      n_edges, n4, pblocks);
        gather32_kernel<<<NB * 4, 256, 0, stream>>>(feat, bases, pairs, out, N_NODES);
    }
}